// Round 2
// baseline (271.241 us; speedup 1.0000x reference)
//
#include <hip/hip_runtime.h>

#define Bb 8
#define Cc 64
#define Hh 200
#define Ww 320
#define Nn 48
#define WDd 80

// ---------------------------------------------------------------------------
// Kernel 1: per (b,n) — gather row idx, mean over WD, vk = Wk·kf_mean + bk,
// then fold through Wf/bf:  WeffT[b][c'][n] = sum_c vk[c]*Wf[c][c']
//                           beff[b][n]     = sum_c vk[c]*bf[c] + vk[64]
// v2: coalesced kf reads via LDS transpose; Wk staged in LDS (pitch 65,
// 2-way bank aliasing = free); butterfly reductions for scalar tails.
// ---------------------------------------------------------------------------
__global__ __launch_bounds__(64) void prep_kernel(
    const float* __restrict__ kf, const float* __restrict__ Wk,
    const float* __restrict__ bk, const float* __restrict__ Wf,
    const float* __restrict__ bf, const float* __restrict__ db,
    const int* __restrict__ pad_w,
    float* __restrict__ weffT, float* __restrict__ beff,
    float* __restrict__ centers)
{
    const int n = blockIdx.x, b = blockIdx.y, tid = threadIdx.x;
    const float stride = (float)pad_w[0] / (float)Ww;   // = 4.0
    const float yc = (db[(b*Nn + n)*4 + 1] + db[(b*Nn + n)*4 + 3]) / (2.0f * stride);
    const int idx = (int)yc;   // trunc, matches astype(int32); always in [0,H)

    __shared__ float buf[65*65];   // reused: kf transpose tile, then Wk staging
    __shared__ float kfm[Cc];
    __shared__ float vk[Cc + 1];

    // Phase A: coalesced kf reads. buf[c*65 + t] = kf[b,c,idx,t] (+ tail t+64)
    const float* __restrict__ kfb = kf + ((size_t)b*Cc*Hh + idx)*WDd;
    #pragma unroll 4
    for (int c = 0; c < Cc; ++c) {
        const float* __restrict__ p = kfb + (size_t)c*Hh*WDd;
        float v = p[tid];                       // lanes consecutive: coalesced
        if (tid < (WDd - 64)) v += p[64 + tid]; // tail 16 elements
        buf[c*65 + tid] = v;
    }
    __syncthreads();

    // Phase A2: kfm[t] = mean over w. Row read: bank=(65t+j)%32=(t+j)%32 ->
    // lanes t,t+32 alias (2-way, free).
    {
        float s = 0.f;
        #pragma unroll 8
        for (int j = 0; j < Cc; ++j) s += buf[tid*65 + j];
        kfm[tid] = s * (1.0f / (float)WDd);
    }
    __syncthreads();   // all reads of buf done before Wk overwrites it

    // Phase B: stage Wk (65 rows x 64 cols) into buf with pitch 65,
    // coalesced global reads: row o=g/64, col c=g&63 -> o*65+c = g + g/64.
    for (int g = tid; g < 65*Cc; g += 64)
        buf[g + (g >> 6)] = Wk[g];
    __syncthreads();

    const float kfm_t = kfm[tid];
    {
        // vk[o=tid] = bk[tid] + Wk[tid,:]·kfm   (LDS reads 2-way, free)
        float a = bk[tid];
        #pragma unroll 8
        for (int c = 0; c < Cc; ++c) a = fmaf(buf[tid*65 + c], kfm[c], a);
        vk[tid] = a;

        // o = 64 row via all-lane partial + butterfly reduce
        float e = buf[64*65 + tid] * kfm_t;
        #pragma unroll
        for (int off = 32; off > 0; off >>= 1) e += __shfl_down(e, off);
        if (tid == 0) vk[Cc] = e + bk[Cc];
    }
    __syncthreads();

    // Phase C: WeffT[b][c'=tid][n] = sum_c vk[c]*Wf[c][c']  (Wf coalesced)
    float wsum = 0.f;
    #pragma unroll 8
    for (int c = 0; c < Cc; ++c) wsum = fmaf(vk[c], Wf[c*Cc + tid], wsum);
    weffT[((size_t)b*Cc + tid)*Nn + n] = wsum;

    // beff[b][n] = sum_c vk[c]*bf[c] + vk[64]  via butterfly reduce
    float e2 = vk[tid] * bf[tid];
    #pragma unroll
    for (int off = 32; off > 0; off >>= 1) e2 += __shfl_down(e2, off);
    if (tid == 0) {
        beff[b*Nn + n] = e2 + vk[Cc];
        centers[b*Nn + n] = yc * stride;
    }
}

// ---------------------------------------------------------------------------
// Kernel 2: logits[b,n,h,w] = sum_c WeffT[b][c][n]*feats[b,c,h,w] + beff[b,n]
// masked with -1e8. One wave per 64 consecutive w. acc[48] in VGPRs.
// REVERTED byte-identical to the round-0 measured-good version:
// 64-thread blocks, plain (cached) stores. The round-1 variants
// (nontemporal stores + 4-row blocks) regressed ~15 us — post-mortem
// pins the write-path change as prime suspect on this write-bound kernel.
// Weight reads are wave-uniform (b, c uniform) -> s_load + v_fmac sgpr-src.
// __ballot makes the skip branch wave-uniform: fully masked waves do no
// feats reads and no FMAs (~65% of pixels are masked).
// ---------------------------------------------------------------------------
__global__ __launch_bounds__(64) void logits_kernel(
    const float* __restrict__ feats, const int* __restrict__ ishape,
    const int* __restrict__ pad_w, const float* __restrict__ weffT,
    const float* __restrict__ beff, float* __restrict__ out)
{
    const int b = blockIdx.z;
    const int h = blockIdx.y;
    const int w = blockIdx.x * 64 + threadIdx.x;

    const float stride = (float)pad_w[0] / (float)Ww;
    const int hlim = (int)((float)ishape[b*2 + 1] / stride);
    const int wlim = (int)((float)ishape[b*2 + 0] / stride);
    const bool act = (h < hlim) && (w < wlim);

    float acc[Nn];
    if (__ballot(act) != 0ULL) {            // wave-uniform branch
        const float* __restrict__ bv = beff + b*Nn;
        #pragma unroll
        for (int n = 0; n < Nn; ++n) acc[n] = bv[n];

        const float* __restrict__ fp = feats + ((size_t)(b*Cc)*Hh + h)*Ww + w;
        const float* __restrict__ wT = weffT + (size_t)b*Cc*Nn;
        #pragma unroll 4
        for (int c = 0; c < Cc; ++c) {
            const float fv = fp[(size_t)c * (Hh*Ww)];
            const float* __restrict__ wrow = wT + c*Nn;
            #pragma unroll
            for (int n = 0; n < Nn; ++n) acc[n] = fmaf(wrow[n], fv, acc[n]);
        }
    } else {
        #pragma unroll
        for (int n = 0; n < Nn; ++n) acc[n] = -1e8f;
    }

    float* op = out + ((size_t)(b*Nn)*Hh + h)*Ww + w;
    #pragma unroll
    for (int n = 0; n < Nn; ++n)
        op[(size_t)n * (Hh*Ww)] = act ? acc[n] : -1e8f;
}

extern "C" void kernel_launch(void* const* d_in, const int* in_sizes, int n_in,
                              void* d_out, int out_size, void* d_ws, size_t ws_size,
                              hipStream_t stream) {
    const float* feats  = (const float*)d_in[0];
    const float* kf     = (const float*)d_in[1];
    const float* Wk     = (const float*)d_in[2];
    const float* bk     = (const float*)d_in[3];
    const float* Wf     = (const float*)d_in[4];
    const float* bf     = (const float*)d_in[5];
    const float* db     = (const float*)d_in[6];
    const int*   ishape = (const int*)d_in[7];
    const int*   pad_w  = (const int*)d_in[8];

    float* out    = (float*)d_out;
    float* weffT  = (float*)d_ws;                      // B*64*48 floats
    float* beff   = weffT + (size_t)Bb*Cc*Nn;          // B*48 floats
    float* centers = out + (size_t)Bb*Nn*Hh*Ww;        // second output

    prep_kernel<<<dim3(Nn, Bb), 64, 0, stream>>>(
        kf, Wk, bk, Wf, bf, db, pad_w, weffT, beff, centers);

    logits_kernel<<<dim3(Ww/64, Hh, Bb), 64, 0, stream>>>(
        feats, ishape, pad_w, weffT, beff, out);
}

// Round 3
// 249.313 us; speedup vs baseline: 1.0880x; 1.0880x over previous
//
#include <hip/hip_runtime.h>

#define Bb 8
#define Cc 64
#define Hh 200
#define Ww 320
#define Nn 48
#define WDd 80

// ---------------------------------------------------------------------------
// Kernel 1: per (b,n) — gather row idx, mean over WD, vk = Wk·kf_mean + bk,
// then fold through Wf/bf:  WeffT[b][c'][n] = sum_c vk[c]*Wf[c][c']
//                           beff[b][n]     = sum_c vk[c]*bf[c] + vk[64]
// Also writes centers output. 384 blocks of 64 threads.
//
// NOTE (round-2 post-mortem): do NOT "fix" the lane-divergent row reads
// below into coalesced+LDS-transposed form. This kernel is 1 wave/block
// with no TLP; the fully-unrolled divergent burst gives 64 concurrent
// cache-line requests per load instruction (one HBM round-trip total),
// whereas the coalesced version serializes ~80 load->ds_write round-trips
// and measured ~20 us SLOWER (248.3 -> 270/271 us across two runs each).
// ---------------------------------------------------------------------------
__global__ __launch_bounds__(64) void prep_kernel(
    const float* __restrict__ kf, const float* __restrict__ Wk,
    const float* __restrict__ bk, const float* __restrict__ Wf,
    const float* __restrict__ bf, const float* __restrict__ db,
    const int* __restrict__ pad_w,
    float* __restrict__ weffT, float* __restrict__ beff,
    float* __restrict__ centers)
{
    const int n = blockIdx.x, b = blockIdx.y, tid = threadIdx.x;
    const float stride = (float)pad_w[0] / (float)Ww;   // = 4.0
    const float yc = (db[(b*Nn + n)*4 + 1] + db[(b*Nn + n)*4 + 3]) / (2.0f * stride);
    const int idx = (int)yc;   // trunc, matches astype(int32); always in [0,H)

    __shared__ float kfm[Cc];
    __shared__ float vk[Cc + 1];

    // mean over WD of kernel_feats[b, tid, idx, :]
    const float* row = kf + ((size_t)(b*Cc + tid)*Hh + idx)*WDd;
    float s = 0.f;
    #pragma unroll
    for (int w0 = 0; w0 < WDd; ++w0) s += row[w0];
    kfm[tid] = s * (1.0f / (float)WDd);
    __syncthreads();

    // vk[o] = bk[o] + Wk[o,:]·kfm   (o = tid, plus o = 64 done by tid 0)
    {
        float a = bk[tid];
        #pragma unroll 8
        for (int c = 0; c < Cc; ++c) a = fmaf(Wk[tid*Cc + c], kfm[c], a);
        vk[tid] = a;
        if (tid == 0) {
            float a2 = bk[Cc];
            for (int c = 0; c < Cc; ++c) a2 = fmaf(Wk[Cc*Cc + c], kfm[c], a2);
            vk[Cc] = a2;
        }
    }
    __syncthreads();

    // WeffT[b][c'][n] = sum_c vk[c] * Wf[c][c']   (c' = tid)
    float wsum = 0.f;
    #pragma unroll 8
    for (int c = 0; c < Cc; ++c) wsum = fmaf(vk[c], Wf[c*Cc + tid], wsum);
    weffT[((size_t)b*Cc + tid)*Nn + n] = wsum;

    if (tid == 0) {
        float bb2 = vk[Cc];
        for (int c = 0; c < Cc; ++c) bb2 = fmaf(vk[c], bf[c], bb2);
        beff[b*Nn + n] = bb2;
        centers[b*Nn + n] = yc * stride;
    }
}

// ---------------------------------------------------------------------------
// Kernel 2: logits[b,n,h,w] = sum_c WeffT[b][c][n]*feats[b,c,h,w] + beff[b,n]
// masked with -1e8. One wave per 64 consecutive w. acc[48] in VGPRs.
// Weight reads are wave-uniform (b, c uniform) -> s_load + v_fmac sgpr-src.
// __ballot makes the skip branch wave-uniform: fully masked waves do no
// feats reads and no FMAs (~65% of pixels are masked).
// Measured-good config: 64-thread blocks, plain cached stores.
// ---------------------------------------------------------------------------
__global__ __launch_bounds__(64) void logits_kernel(
    const float* __restrict__ feats, const int* __restrict__ ishape,
    const int* __restrict__ pad_w, const float* __restrict__ weffT,
    const float* __restrict__ beff, float* __restrict__ out)
{
    const int b = blockIdx.z;
    const int h = blockIdx.y;
    const int w = blockIdx.x * 64 + threadIdx.x;

    const float stride = (float)pad_w[0] / (float)Ww;
    const int hlim = (int)((float)ishape[b*2 + 1] / stride);
    const int wlim = (int)((float)ishape[b*2 + 0] / stride);
    const bool act = (h < hlim) && (w < wlim);

    float acc[Nn];
    if (__ballot(act) != 0ULL) {            // wave-uniform branch
        const float* __restrict__ bv = beff + b*Nn;
        #pragma unroll
        for (int n = 0; n < Nn; ++n) acc[n] = bv[n];

        const float* __restrict__ fp = feats + ((size_t)(b*Cc)*Hh + h)*Ww + w;
        const float* __restrict__ wT = weffT + (size_t)b*Cc*Nn;
        #pragma unroll 4
        for (int c = 0; c < Cc; ++c) {
            const float fv = fp[(size_t)c * (Hh*Ww)];
            const float* __restrict__ wrow = wT + c*Nn;
            #pragma unroll
            for (int n = 0; n < Nn; ++n) acc[n] = fmaf(wrow[n], fv, acc[n]);
        }
    } else {
        #pragma unroll
        for (int n = 0; n < Nn; ++n) acc[n] = -1e8f;
    }

    float* op = out + ((size_t)(b*Nn)*Hh + h)*Ww + w;
    #pragma unroll
    for (int n = 0; n < Nn; ++n)
        op[(size_t)n * (Hh*Ww)] = act ? acc[n] : -1e8f;
}

extern "C" void kernel_launch(void* const* d_in, const int* in_sizes, int n_in,
                              void* d_out, int out_size, void* d_ws, size_t ws_size,
                              hipStream_t stream) {
    const float* feats  = (const float*)d_in[0];
    const float* kf     = (const float*)d_in[1];
    const float* Wk     = (const float*)d_in[2];
    const float* bk     = (const float*)d_in[3];
    const float* Wf     = (const float*)d_in[4];
    const float* bf     = (const float*)d_in[5];
    const float* db     = (const float*)d_in[6];
    const int*   ishape = (const int*)d_in[7];
    const int*   pad_w  = (const int*)d_in[8];

    float* out    = (float*)d_out;
    float* weffT  = (float*)d_ws;                      // B*64*48 floats
    float* beff   = weffT + (size_t)Bb*Cc*Nn;          // B*48 floats
    float* centers = out + (size_t)Bb*Nn*Hh*Ww;        // second output

    prep_kernel<<<dim3(Nn, Bb), 64, 0, stream>>>(
        kf, Wk, bk, Wf, bf, db, pad_w, weffT, beff, centers);

    logits_kernel<<<dim3(Ww/64, Hh, Bb), 64, 0, stream>>>(
        feats, ishape, pad_w, weffT, beff, out);
}